// Round 18
// baseline (92.737 us; speedup 1.0000x reference)
//
#include <hip/hip_runtime.h>

#define B_   4
#define CIN  64
#define COUT 64
#define H_   128
#define W_   128
#define NOFF 18      // 2*N offset channels
#define HW   (H_ * W_)
#define HP   130
#define WP   130

typedef __attribute__((ext_vector_type(8))) short bf16x8;
typedef __attribute__((ext_vector_type(4))) float f32x4;

__device__ __forceinline__ unsigned short f2bf(float f) {
    unsigned int u = __float_as_uint(f);
    return (unsigned short)((u + 0x7fffu + ((u >> 16) & 1u)) >> 16);
}

// ---------------------------------------------------------------------------
// k_prep (r16-proven prep + r13-proven weight packing folded in):
//  all blocks : x f32 -> xt bf16 AND xt2 u32 pair-packed (one pass)
//  blocks 0-26: additionally pack wB / wBo into MFMA B-frag order
// grid = B*HP = 520 blocks of 256.
// ---------------------------------------------------------------------------
__global__ __launch_bounds__(256) void k_prep(
    const float* __restrict__ x, unsigned short* __restrict__ xt,
    unsigned int* __restrict__ xt2,
    const float* __restrict__ w_def, const float* __restrict__ w_off,
    unsigned short* __restrict__ wB, unsigned short* __restrict__ wBo)
{
    // ---- weight packing (first 27 blocks; indices guarded) ----
    const int i = blockIdx.x * 256 + threadIdx.x;
    if (i < 18 * 4 * 64) {
        const int kblk = i >> 8;
        const int nblk = (i >> 6) & 3;
        const int lane = i & 63;
        const int o = nblk * 16 + (lane & 15);
        unsigned int pk[4];
#pragma unroll
        for (int d = 0; d < 4; ++d) {
            unsigned int v = 0;
#pragma unroll
            for (int e = 0; e < 2; ++e) {
                const int K = kblk * 32 + 8 * (lane >> 4) + d * 2 + e;
                const int n = K >> 6, c = K & 63;
                v |= (unsigned int)f2bf(w_def[((size_t)o * 64 + c) * 9 + n]) << (16 * e);
            }
            pk[d] = v;
        }
        *(uint4*)(wB + (size_t)i * 8) = make_uint4(pk[0], pk[1], pk[2], pk[3]);
    }
    const int j = i - 18 * 4 * 64;
    if (j >= 0 && j < 18 * 2 * 64) {
        const int kblk = j >> 7;
        const int nblk = (j >> 6) & 1;
        const int lane = j & 63;
        const int o = nblk * 16 + (lane & 15);
        unsigned int pk[4];
#pragma unroll
        for (int d = 0; d < 4; ++d) {
            unsigned int v = 0;
#pragma unroll
            for (int e = 0; e < 2; ++e) {
                const int K = kblk * 32 + 8 * (lane >> 4) + d * 2 + e;
                const int n = K >> 6, c = K & 63;
                const float wv = (o < NOFF) ? w_off[((size_t)o * 64 + c) * 9 + n] : 0.f;
                v |= (unsigned int)f2bf(wv) << (16 * e);
            }
            pk[d] = v;
        }
        *(uint4*)(wBo + (size_t)j * 8) = make_uint4(pk[0], pk[1], pk[2], pk[3]);
    }

    // ---- xt / xt2 prep (r16 proven) ----
    const int b  = blockIdx.x / HP;
    const int hp = blockIdx.x - b * HP;
    const int c  = threadIdx.x & 63;
    const int wq = threadIdx.x >> 6;
    const float* xr = x + (((size_t)b * CIN + c) * H_ + (hp - 1)) * W_;
    unsigned short* d1 = xt  + (((size_t)b * HP + hp) * WP) * 64 + c;
    unsigned int*   d2 = xt2 + (((size_t)b * HP + hp) * WP) * 64 + c;
    const bool hin = (hp >= 1 && hp <= H_);
    for (int wp = wq; wp < WP; wp += 4) {
        float v1 = 0.f, v2 = 0.f;
        if (hin) {
            if (wp >= 1 && wp <= W_)         v1 = xr[wp - 1];
            if (wp + 1 >= 1 && wp + 1 <= W_) v2 = xr[wp];
        }
        const unsigned int a1 = f2bf(v1), a2 = f2bf(v2);
        d1[(size_t)wp * 64] = (unsigned short)a1;
        d2[(size_t)wp * 64] = a1 | (a2 << 16);
    }
}

// ---------------------------------------------------------------------------
// k_fuse2: phase 0 = offconv MFMA -> off_s LDS (r16-proven path, 32-px
// re-index, waves 0-1); phase 1 = geometry (r15 verbatim, source off_s);
// phase 2 = pair-load gather (r15 verbatim); phase 3 = r4-proven GEMM
// (waves 0-1). grid = B*HW/32 = 2048 blocks of 256 (32 px/block).
// ---------------------------------------------------------------------------
__global__ __launch_bounds__(256) void k_fuse2(
    const unsigned short* __restrict__ xt, const unsigned int* __restrict__ xt2,
    const unsigned short* __restrict__ wBo, const unsigned short* __restrict__ wB,
    const float* __restrict__ b_off, const float* __restrict__ b_def,
    unsigned short* __restrict__ xoff, float* __restrict__ out)
{
    __shared__ float  off_s[NOFF][33];   // +1 pad: conflict-free col access
    __shared__ uint2  geoI[9][32];       // byte offsets of (row xl, row xr)
    __shared__ float4 geoG[9][32];       // (wyl, wyr, gxl, gxr)

    const int tid   = threadIdx.x;
    const int lane  = tid & 63;
    const int wv    = tid >> 6;
    const int pxblk = ((blockIdx.x & 7) << 8) | (blockIdx.x >> 3);  // XCD swizzle
    const int b     = pxblk >> 9;
    const int h     = (pxblk >> 2) & 127;
    const int w0    = (pxblk & 3) * 32;

    // ---- phase 0: offset conv (r13/r16-proven MFMA), waves 0-1 ----
    if (wv < 2) {
        const int row = lane & 15;
        const int g   = lane >> 4;
        const unsigned short* xtb = xt + (size_t)b * (HP * WP * 64);
        const unsigned short* Bp  = wBo + (size_t)lane * 8;
        f32x4 acc0 = {0.f, 0.f, 0.f, 0.f};
        f32x4 acc1 = {0.f, 0.f, 0.f, 0.f};
#pragma unroll
        for (int kb = 0; kb < 18; ++kb) {
            const int n  = kb >> 1;
            const int hp = h + n / 3;
            const int wp = w0 + wv * 16 + row + (n % 3);
            const int cb = (kb & 1) * 32 + g * 8;
            const bf16x8 a  = *(const bf16x8*)(xtb + ((size_t)hp * WP + wp) * 64 + cb);
            const bf16x8 b0 = *(const bf16x8*)(Bp + (size_t)(kb * 2 + 0) * 512);
            const bf16x8 b1 = *(const bf16x8*)(Bp + (size_t)(kb * 2 + 1) * 512);
            acc0 = __builtin_amdgcn_mfma_f32_16x16x32_bf16(a, b0, acc0, 0, 0, 0);
            acc1 = __builtin_amdgcn_mfma_f32_16x16x32_bf16(a, b1, acc1, 0, 0, 0);
        }
        // D: col = lane&15 = k, row = 4*g+reg = px_local (within wave's 16)
        const int pxb = wv * 16 + 4 * g;
        {
            const float bias = b_off[row];
#pragma unroll
            for (int r = 0; r < 4; ++r) off_s[row][pxb + r] = acc0[r] + bias;
        }
        if (row < 2) {
            const float bias = b_off[16 + row];
#pragma unroll
            for (int r = 0; r < 4; ++r) off_s[16 + row][pxb + r] = acc1[r] + bias;
        }
    }
    __syncthreads();

    // ---- phase 1: geometry (r15 verbatim; source = off_s) ----
    if (lane < 32) {
        const int wpix = w0 + lane;
        for (int n = wv; n < 9; n += 4) {
            const float ox = off_s[n][lane];
            const float oy = off_s[n + 9][lane];
            const float px = (float)(h + n / 3) + ox;
            const float py = (float)(wpix + n % 3) + oy;
            const float flx = floorf(px), fly = floorf(py);
            const float qlx = fminf(fmaxf(flx, 0.f), 129.f);
            const float qly = fminf(fmaxf(fly, 0.f), 129.f);
            const float qrx = fminf(fmaxf(flx + 1.f, 0.f), 129.f);
            const float qry = fminf(fmaxf(fly + 1.f, 0.f), 129.f);
            const float pxc = fminf(fmaxf(px, 0.f), 129.f);
            const float pyc = fminf(fmaxf(py, 0.f), 129.f);
            const float gxl = 1.f + (qlx - pxc);
            const float gxr = 1.f - (qrx - pxc);
            const float gyl = 1.f + (qly - pyc);
            const float gyr = 1.f - (qry - pyc);
            const int xl = (int)qlx, yl = (int)qly, xr = (int)qrx, yr = (int)qry;
            float wyl = gyl, wyr = gyr;
            if (yr == yl) { wyl = gyl + gyr; wyr = 0.f; }   // clamped column fold
            geoI[n][lane] = make_uint2((unsigned)((xl * WP + yl) * 256),
                                       (unsigned)((xr * WP + yl) * 256));
            geoG[n][lane] = make_float4(wyl, wyr, gxl, gxr);
        }
    }
    __syncthreads();

    // ---- phase 2: gather (r15 verbatim; lane = channel, pair-loads) ----
    const char* xtb4 = (const char*)(xt2 + (size_t)b * (HP * WP * 64)) + lane * 4;
    unsigned short* xo = xoff + (size_t)(pxblk * 32) * 576;

#pragma unroll 1
    for (int pxi = 0; pxi < 8; ++pxi) {
        const int pxl = wv * 8 + pxi;
#pragma unroll 3
        for (int n = 0; n < 9; ++n) {
            const uint2  gi = geoI[n][pxl];
            const float4 gg = geoG[n][pxl];
            const unsigned int u1 = *(const unsigned int*)(xtb4 + gi.x);
            const unsigned int u2 = *(const unsigned int*)(xtb4 + gi.y);
            const float s0 = __uint_as_float(u1 << 16);
            const float s1 = __uint_as_float(u1 & 0xffff0000u);
            const float t0 = __uint_as_float(u2 << 16);
            const float t1 = __uint_as_float(u2 & 0xffff0000u);
            const float r1 = fmaf(gg.x, s0, gg.y * s1);   // row xl
            const float r2 = fmaf(gg.x, t0, gg.y * t1);   // row xr
            const float v  = fmaf(gg.z, r1, gg.w * r2);
            xo[(size_t)pxl * 576 + n * 64 + lane] = f2bf(v);
        }
    }

    // drain stores, then waves 0-1 consume this block's xoff slice from L2.
    __syncthreads();
    if (wv >= 2) return;

    // ---- phase 3: GEMM (r4-proven k_gemm inner loop, verbatim) ----
    const int row = lane & 15;
    const int g   = lane >> 4;

    const unsigned short* Ap = xoff + (size_t)(pxblk * 32 + wv * 16 + row) * 576 + g * 8;
    const unsigned short* Bp = wB + (size_t)lane * 8;

    f32x4 acc0 = {0.f, 0.f, 0.f, 0.f};
    f32x4 acc1 = {0.f, 0.f, 0.f, 0.f};
    f32x4 acc2 = {0.f, 0.f, 0.f, 0.f};
    f32x4 acc3 = {0.f, 0.f, 0.f, 0.f};

#pragma unroll 3
    for (int kb = 0; kb < 18; ++kb) {
        const bf16x8 a  = *(const bf16x8*)(Ap + kb * 32);
        const bf16x8 b0 = *(const bf16x8*)(Bp + (size_t)(kb * 4 + 0) * 512);
        const bf16x8 b1 = *(const bf16x8*)(Bp + (size_t)(kb * 4 + 1) * 512);
        const bf16x8 b2 = *(const bf16x8*)(Bp + (size_t)(kb * 4 + 2) * 512);
        const bf16x8 b3 = *(const bf16x8*)(Bp + (size_t)(kb * 4 + 3) * 512);
        acc0 = __builtin_amdgcn_mfma_f32_16x16x32_bf16(a, b0, acc0, 0, 0, 0);
        acc1 = __builtin_amdgcn_mfma_f32_16x16x32_bf16(a, b1, acc1, 0, 0, 0);
        acc2 = __builtin_amdgcn_mfma_f32_16x16x32_bf16(a, b2, acc2, 0, 0, 0);
        acc3 = __builtin_amdgcn_mfma_f32_16x16x32_bf16(a, b3, acc3, 0, 0, 0);
    }

    const int p_base = pxblk * 32 + wv * 16 + 4 * g;
#pragma unroll
    for (int i = 0; i < 4; ++i) {
        const int o = i * 16 + row;
        const float bias = b_def[o];
        const f32x4 A = (i == 0) ? acc0 : (i == 1) ? acc1 : (i == 2) ? acc2 : acc3;
#pragma unroll
        for (int r = 0; r < 4; ++r) {
            const int p  = p_base + r;
            const int bb = p >> 14;
            const int hw = p & 16383;
            out[((size_t)(bb * COUT + o)) * HW + hw] = A[r] + bias;
        }
    }
}

// ===========================================================================
extern "C" void kernel_launch(void* const* d_in, const int* in_sizes, int n_in,
                              void* d_out, int out_size, void* d_ws, size_t ws_size,
                              hipStream_t stream)
{
    const float* x     = (const float*)d_in[0];
    const float* w_off = (const float*)d_in[1];
    const float* b_off = (const float*)d_in[2];
    const float* w_def = (const float*)d_in[3];
    const float* b_def = (const float*)d_in[4];
    float* out = (float*)d_out;

    char* ws = (char*)d_ws;
    // wB   : bf16 36,864                    73,728 B @ 0
    // wBo  : bf16 18,432                    36,864 B @ 73,728
    // xt   : bf16 [B][130][130][64]      8,652,800 B @ 110,592
    // xt2  : u32  [B][130][130][64]     17,305,600 B @ 8,763,392
    // xoff : bf16 65536 x 576           75,497,472 B @ 26,068,992
    unsigned short* wB   = (unsigned short*)(ws + 0);
    unsigned short* wBo  = (unsigned short*)(ws + 73728);
    unsigned short* xt   = (unsigned short*)(ws + 110592);
    unsigned int*   xt2  = (unsigned int*)(ws + 8763392);
    unsigned short* xoff = (unsigned short*)(ws + 26068992);

    k_prep<<<B_ * HP, 256, 0, stream>>>(x, xt, xt2, w_def, w_off, wB, wBo);
    k_fuse2<<<B_ * HW / 32, 256, 0, stream>>>(xt, xt2, wBo, wB, b_off, b_def,
                                              xoff, out);
}

// Round 19
// 86.316 us; speedup vs baseline: 1.0744x; 1.0744x over previous
//
#include <hip/hip_runtime.h>

#define B_   4
#define CIN  64
#define COUT 64
#define H_   128
#define W_   128
#define NOFF 18      // 2*N offset channels
#define HW   (H_ * W_)
#define HP   130
#define WP   130

typedef __attribute__((ext_vector_type(8))) short bf16x8;
typedef __attribute__((ext_vector_type(4))) float f32x4;

__device__ __forceinline__ unsigned short f2bf(float f) {
    unsigned int u = __float_as_uint(f);
    return (unsigned short)((u + 0x7fffu + ((u >> 16) & 1u)) >> 16);
}
__device__ __forceinline__ float bf2f(unsigned short s) {
    return __uint_as_float(((unsigned int)s) << 16);
}

// ---------------------------------------------------------------------------
// k_wt (r13/r14 proven): pack BOTH weight tensors into MFMA B-frag order.
//  wB  [kblk(18)][nblk(4)][lane][8] : einsum weights
//  wBo [kblk(18)][nblk(2)][lane][8] : offset-conv weights, N padded 18->32
// ---------------------------------------------------------------------------
__global__ __launch_bounds__(256) void k_wt(
    const float* __restrict__ w_def, const float* __restrict__ w_off,
    unsigned short* __restrict__ wB, unsigned short* __restrict__ wBo)
{
    const int i = blockIdx.x * 256 + threadIdx.x;
    if (i < 18 * 4 * 64) {
        const int kblk = i >> 8;
        const int nblk = (i >> 6) & 3;
        const int lane = i & 63;
        const int o = nblk * 16 + (lane & 15);
        unsigned int pk[4];
#pragma unroll
        for (int d = 0; d < 4; ++d) {
            unsigned int v = 0;
#pragma unroll
            for (int e = 0; e < 2; ++e) {
                const int K = kblk * 32 + 8 * (lane >> 4) + d * 2 + e;
                const int n = K >> 6, c = K & 63;
                v |= (unsigned int)f2bf(w_def[((size_t)o * 64 + c) * 9 + n]) << (16 * e);
            }
            pk[d] = v;
        }
        *(uint4*)(wB + (size_t)i * 8) = make_uint4(pk[0], pk[1], pk[2], pk[3]);
    }
    const int j = i - 18 * 4 * 64;
    if (j >= 0 && j < 18 * 2 * 64) {
        const int kblk = j >> 7;
        const int nblk = (j >> 6) & 1;
        const int lane = j & 63;
        const int o = nblk * 16 + (lane & 15);
        unsigned int pk[4];
#pragma unroll
        for (int d = 0; d < 4; ++d) {
            unsigned int v = 0;
#pragma unroll
            for (int e = 0; e < 2; ++e) {
                const int K = kblk * 32 + 8 * (lane >> 4) + d * 2 + e;
                const int n = K >> 6, c = K & 63;
                const float wv = (o < NOFF) ? w_off[((size_t)o * 64 + c) * 9 + n] : 0.f;
                v |= (unsigned int)f2bf(wv) << (16 * e);
            }
            pk[d] = v;
        }
        *(uint4*)(wBo + (size_t)j * 8) = make_uint4(pk[0], pk[1], pk[2], pk[3]);
    }
}

// ---------------------------------------------------------------------------
// k_xt (r12-r14 proven): x f32 -> xt bf16 [B][130][130][64].
// ---------------------------------------------------------------------------
__global__ __launch_bounds__(256) void k_xt(
    const float* __restrict__ x, unsigned short* __restrict__ xt)
{
    const int b  = blockIdx.x / HP;
    const int hp = blockIdx.x - b * HP;
    const int c  = threadIdx.x & 63;
    const int wq = threadIdx.x >> 6;
    unsigned short* dst = xt + (((size_t)b * HP + hp) * WP) * 64 + c;
    for (int wp = wq; wp < WP; wp += 4) {
        float v = 0.f;
        if (hp >= 1 && hp <= H_ && wp >= 1 && wp <= W_)
            v = x[(((size_t)b * CIN + c) * H_ + (hp - 1)) * W_ + (wp - 1)];
        dst[(size_t)wp * 64] = f2bf(v);
    }
}

// ---------------------------------------------------------------------------
// k_offconv_mfma (r13/r14 proven): 3x3 offset conv as implicit-im2col MFMA.
// ---------------------------------------------------------------------------
__global__ __launch_bounds__(256) void k_offconv_mfma(
    const unsigned short* __restrict__ xt, const unsigned short* __restrict__ wBo,
    const float* __restrict__ b_off, float* __restrict__ off)
{
    const int tid  = threadIdx.x;
    const int lane = tid & 63;
    const int wv   = tid >> 6;
    const int row  = lane & 15;
    const int g    = lane >> 4;

    const int p0 = blockIdx.x * 64 + wv * 16;
    const int b  = p0 >> 14;
    const int h  = (p0 >> 7) & 127;
    const int w0 = p0 & 127;

    const unsigned short* xtb = xt + (size_t)b * (HP * WP * 64);
    const unsigned short* Bp  = wBo + (size_t)lane * 8;

    f32x4 acc0 = {0.f, 0.f, 0.f, 0.f};
    f32x4 acc1 = {0.f, 0.f, 0.f, 0.f};

#pragma unroll
    for (int kb = 0; kb < 18; ++kb) {
        const int n  = kb >> 1;
        const int hp = h + n / 3;
        const int wp = w0 + row + (n % 3);
        const int cb = (kb & 1) * 32 + g * 8;
        const bf16x8 a  = *(const bf16x8*)(xtb + ((size_t)hp * WP + wp) * 64 + cb);
        const bf16x8 b0 = *(const bf16x8*)(Bp + (size_t)(kb * 2 + 0) * 512);
        const bf16x8 b1 = *(const bf16x8*)(Bp + (size_t)(kb * 2 + 1) * 512);
        acc0 = __builtin_amdgcn_mfma_f32_16x16x32_bf16(a, b0, acc0, 0, 0, 0);
        acc1 = __builtin_amdgcn_mfma_f32_16x16x32_bf16(a, b1, acc1, 0, 0, 0);
    }

    const int hwb = (p0 + 4 * g) & 16383;
    {
        const int o = row;
        float4 v = make_float4(acc0[0] + b_off[o], acc0[1] + b_off[o],
                               acc0[2] + b_off[o], acc0[3] + b_off[o]);
        *(float4*)&off[((size_t)b * NOFF + o) * HW + hwb] = v;
    }
    if (row < 2) {
        const int o = 16 + row;
        float4 v = make_float4(acc1[0] + b_off[o], acc1[1] + b_off[o],
                               acc1[2] + b_off[o], acc1[3] + b_off[o]);
        *(float4*)&off[((size_t)b * NOFF + o) * HW + hwb] = v;
    }
}

// ---------------------------------------------------------------------------
// k_fuse (r14 proven, 86.2 us): gather -> global xoff (block's slice, L2-hot)
// -> __syncthreads (drains stores) -> r4-proven GEMM on waves 0-1.
// grid = B*HW/32 = 2048 blocks of 256 (32 px/block).
// ---------------------------------------------------------------------------
__global__ __launch_bounds__(256) void k_fuse(
    const unsigned short* __restrict__ xt, const float* __restrict__ off,
    unsigned short* __restrict__ xoff, const unsigned short* __restrict__ wB,
    const float* __restrict__ b_def, float* __restrict__ out)
{
    const int tid   = threadIdx.x;
    const int lane  = tid & 63;
    const int wv    = tid >> 6;
    const int pxblk = blockIdx.x;
    const int b     = pxblk >> 9;
    const int h     = (pxblk >> 2) & 127;
    const int w0    = (pxblk & 3) * 32;

    __shared__ uint4  geoI[9][32];    // byte offsets into xt[b] (idx*128)
    __shared__ float4 geoG[9][32];

    // ---- phase 1: geometry (lane = pixel), r4-proven formulas ----
    if (lane < 32) {
        const int wpix = w0 + lane;
        const float* offp = off + ((size_t)b * NOFF) * HW + h * W_ + wpix;
        for (int n = wv; n < 9; n += 4) {
            const float ox = offp[(size_t)n * HW];
            const float oy = offp[(size_t)(n + 9) * HW];
            const float px = (float)(h + n / 3) + ox;
            const float py = (float)(wpix + n % 3) + oy;
            const float flx = floorf(px), fly = floorf(py);
            const float qlx = fminf(fmaxf(flx, 0.f), 129.f);
            const float qly = fminf(fmaxf(fly, 0.f), 129.f);
            const float qrx = fminf(fmaxf(flx + 1.f, 0.f), 129.f);
            const float qry = fminf(fmaxf(fly + 1.f, 0.f), 129.f);
            const float pxc = fminf(fmaxf(px, 0.f), 129.f);
            const float pyc = fminf(fmaxf(py, 0.f), 129.f);
            const float gxl = 1.f + (qlx - pxc);
            const float gxr = 1.f - (qrx - pxc);
            const float gyl = 1.f + (qly - pyc);
            const float gyr = 1.f - (qry - pyc);
            const int xl = (int)qlx, yl = (int)qly, xr = (int)qrx, yr = (int)qry;
            geoI[n][lane] = make_uint4((unsigned)((xl * WP + yl) * 128),
                                       (unsigned)((xr * WP + yr) * 128),
                                       (unsigned)((xl * WP + yr) * 128),
                                       (unsigned)((xr * WP + yl) * 128));
            geoG[n][lane] = make_float4(gxl * gyl, gxr * gyr, gxl * gyr, gxr * gyl);
        }
    }
    __syncthreads();

    // ---- phase 2: gather (lane = channel), coalesced bf16 corner loads ----
    const char* xtb2 = (const char*)(xt + (size_t)b * (HP * WP * 64)) + lane * 2;
    unsigned short* xo = xoff + (size_t)(pxblk * 32) * 576;

#pragma unroll 1
    for (int pxi = 0; pxi < 8; ++pxi) {
        const int pxl = wv * 8 + pxi;
#pragma unroll 3
        for (int n = 0; n < 9; ++n) {
            const uint4  gi = geoI[n][pxl];
            const float4 gg = geoG[n][pxl];
            const float vlt = bf2f(*(const unsigned short*)(xtb2 + gi.x));
            const float vrb = bf2f(*(const unsigned short*)(xtb2 + gi.y));
            const float vlb = bf2f(*(const unsigned short*)(xtb2 + gi.z));
            const float vrt = bf2f(*(const unsigned short*)(xtb2 + gi.w));
            const float v = fmaf(gg.x, vlt, fmaf(gg.y, vrb,
                            fmaf(gg.z, vlb, gg.w * vrt)));
            xo[(size_t)pxl * 576 + n * 64 + lane] = f2bf(v);
        }
    }

    // drain stores (compiler emits s_waitcnt vmcnt(0) before s_barrier),
    // then waves 0-1 consume this block's xoff slice from L2.
    __syncthreads();
    if (wv >= 2) return;

    // ---- phase 3: GEMM (r4-proven k_gemm inner loop, verbatim) ----
    const int row = lane & 15;
    const int g   = lane >> 4;

    const unsigned short* Ap = xoff + (size_t)(pxblk * 32 + wv * 16 + row) * 576 + g * 8;
    const unsigned short* Bp = wB + (size_t)lane * 8;

    f32x4 acc0 = {0.f, 0.f, 0.f, 0.f};
    f32x4 acc1 = {0.f, 0.f, 0.f, 0.f};
    f32x4 acc2 = {0.f, 0.f, 0.f, 0.f};
    f32x4 acc3 = {0.f, 0.f, 0.f, 0.f};

#pragma unroll 3
    for (int kb = 0; kb < 18; ++kb) {
        const bf16x8 a  = *(const bf16x8*)(Ap + kb * 32);
        const bf16x8 b0 = *(const bf16x8*)(Bp + (size_t)(kb * 4 + 0) * 512);
        const bf16x8 b1 = *(const bf16x8*)(Bp + (size_t)(kb * 4 + 1) * 512);
        const bf16x8 b2 = *(const bf16x8*)(Bp + (size_t)(kb * 4 + 2) * 512);
        const bf16x8 b3 = *(const bf16x8*)(Bp + (size_t)(kb * 4 + 3) * 512);
        acc0 = __builtin_amdgcn_mfma_f32_16x16x32_bf16(a, b0, acc0, 0, 0, 0);
        acc1 = __builtin_amdgcn_mfma_f32_16x16x32_bf16(a, b1, acc1, 0, 0, 0);
        acc2 = __builtin_amdgcn_mfma_f32_16x16x32_bf16(a, b2, acc2, 0, 0, 0);
        acc3 = __builtin_amdgcn_mfma_f32_16x16x32_bf16(a, b3, acc3, 0, 0, 0);
    }

    const int p_base = pxblk * 32 + wv * 16 + 4 * g;
#pragma unroll
    for (int i = 0; i < 4; ++i) {
        const int o = i * 16 + row;
        const float bias = b_def[o];
        const f32x4 A = (i == 0) ? acc0 : (i == 1) ? acc1 : (i == 2) ? acc2 : acc3;
#pragma unroll
        for (int r = 0; r < 4; ++r) {
            const int p  = p_base + r;
            const int bb = p >> 14;
            const int hw = p & 16383;
            out[((size_t)(bb * COUT + o)) * HW + hw] = A[r] + bias;
        }
    }
}

// ===========================================================================
extern "C" void kernel_launch(void* const* d_in, const int* in_sizes, int n_in,
                              void* d_out, int out_size, void* d_ws, size_t ws_size,
                              hipStream_t stream)
{
    const float* x     = (const float*)d_in[0];
    const float* w_off = (const float*)d_in[1];
    const float* b_off = (const float*)d_in[2];
    const float* w_def = (const float*)d_in[3];
    const float* b_def = (const float*)d_in[4];
    float* out = (float*)d_out;

    char* ws = (char*)d_ws;
    // wB   : bf16 36,864                    73,728 B @ 0
    // wBo  : bf16 18,432                    36,864 B @ 73,728
    // xt   : bf16 [B][130][130][64]      8,652,800 B @ 110,592
    // off  : f32 [B][18][HW]             4,718,592 B @ 8,763,392
    // xoff : bf16 65536 x 576           75,497,472 B @ 13,481,984
    unsigned short* wB   = (unsigned short*)(ws + 0);
    unsigned short* wBo  = (unsigned short*)(ws + 73728);
    unsigned short* xt   = (unsigned short*)(ws + 110592);
    float*          off  = (float*)(ws + 8763392);
    unsigned short* xoff = (unsigned short*)(ws + 13481984);

    k_wt<<<(18 * 4 * 64 + 18 * 2 * 64 + 255) / 256, 256, 0, stream>>>(
        w_def, w_off, wB, wBo);
    k_xt<<<B_ * HP, 256, 0, stream>>>(x, xt);
    k_offconv_mfma<<<B_ * HW / 64, 256, 0, stream>>>(xt, wBo, b_off, off);
    k_fuse<<<B_ * HW / 32, 256, 0, stream>>>(xt, off, xoff, wB, b_def, out);
}

// Round 20
// 82.108 us; speedup vs baseline: 1.1295x; 1.0513x over previous
//
#include <hip/hip_runtime.h>

#define B_   4
#define CIN  64
#define COUT 64
#define H_   128
#define W_   128
#define NOFF 18      // 2*N offset channels
#define HW   (H_ * W_)
#define HP   130
#define WP   130

typedef __attribute__((ext_vector_type(8))) short bf16x8;
typedef __attribute__((ext_vector_type(4))) float f32x4;

__device__ __forceinline__ unsigned short f2bf(float f) {
    unsigned int u = __float_as_uint(f);
    return (unsigned short)((u + 0x7fffu + ((u >> 16) & 1u)) >> 16);
}
__device__ __forceinline__ float bf2f(unsigned short s) {
    return __uint_as_float(((unsigned int)s) << 16);
}

// ---------------------------------------------------------------------------
// k_prep: weight packing (blocks 0-26, r13-proven mapping) + xt transpose
// (r12-proven). Merged per r18's proven k_prep structure (minus xt2).
// grid = B*HP = 520 blocks of 256.
// ---------------------------------------------------------------------------
__global__ __launch_bounds__(256) void k_prep(
    const float* __restrict__ x, unsigned short* __restrict__ xt,
    const float* __restrict__ w_def, const float* __restrict__ w_off,
    unsigned short* __restrict__ wB, unsigned short* __restrict__ wBo)
{
    // ---- weight packing (first 27 blocks; indices guarded) ----
    const int i = blockIdx.x * 256 + threadIdx.x;
    if (i < 18 * 4 * 64) {
        const int kblk = i >> 8;
        const int nblk = (i >> 6) & 3;
        const int lane = i & 63;
        const int o = nblk * 16 + (lane & 15);
        unsigned int pk[4];
#pragma unroll
        for (int d = 0; d < 4; ++d) {
            unsigned int v = 0;
#pragma unroll
            for (int e = 0; e < 2; ++e) {
                const int K = kblk * 32 + 8 * (lane >> 4) + d * 2 + e;
                const int n = K >> 6, c = K & 63;
                v |= (unsigned int)f2bf(w_def[((size_t)o * 64 + c) * 9 + n]) << (16 * e);
            }
            pk[d] = v;
        }
        *(uint4*)(wB + (size_t)i * 8) = make_uint4(pk[0], pk[1], pk[2], pk[3]);
    }
    const int j = i - 18 * 4 * 64;
    if (j >= 0 && j < 18 * 2 * 64) {
        const int kblk = j >> 7;
        const int nblk = (j >> 6) & 1;
        const int lane = j & 63;
        const int o = nblk * 16 + (lane & 15);
        unsigned int pk[4];
#pragma unroll
        for (int d = 0; d < 4; ++d) {
            unsigned int v = 0;
#pragma unroll
            for (int e = 0; e < 2; ++e) {
                const int K = kblk * 32 + 8 * (lane >> 4) + d * 2 + e;
                const int n = K >> 6, c = K & 63;
                const float wv = (o < NOFF) ? w_off[((size_t)o * 64 + c) * 9 + n] : 0.f;
                v |= (unsigned int)f2bf(wv) << (16 * e);
            }
            pk[d] = v;
        }
        *(uint4*)(wBo + (size_t)j * 8) = make_uint4(pk[0], pk[1], pk[2], pk[3]);
    }

    // ---- xt transpose (r12-r14 proven): x f32 -> xt bf16 [B][130][130][64] ----
    const int b  = blockIdx.x / HP;
    const int hp = blockIdx.x - b * HP;
    const int c  = threadIdx.x & 63;
    const int wq = threadIdx.x >> 6;
    unsigned short* dst = xt + (((size_t)b * HP + hp) * WP) * 64 + c;
    for (int wp = wq; wp < WP; wp += 4) {
        float v = 0.f;
        if (hp >= 1 && hp <= H_ && wp >= 1 && wp <= W_)
            v = x[(((size_t)b * CIN + c) * H_ + (hp - 1)) * W_ + (wp - 1)];
        dst[(size_t)wp * 64] = f2bf(v);
    }
}

// ---------------------------------------------------------------------------
// k_offconv_mfma (r13/r14/r19 proven): 3x3 offset conv as im2col MFMA.
// ---------------------------------------------------------------------------
__global__ __launch_bounds__(256) void k_offconv_mfma(
    const unsigned short* __restrict__ xt, const unsigned short* __restrict__ wBo,
    const float* __restrict__ b_off, float* __restrict__ off)
{
    const int tid  = threadIdx.x;
    const int lane = tid & 63;
    const int wv   = tid >> 6;
    const int row  = lane & 15;
    const int g    = lane >> 4;

    const int p0 = blockIdx.x * 64 + wv * 16;
    const int b  = p0 >> 14;
    const int h  = (p0 >> 7) & 127;
    const int w0 = p0 & 127;

    const unsigned short* xtb = xt + (size_t)b * (HP * WP * 64);
    const unsigned short* Bp  = wBo + (size_t)lane * 8;

    f32x4 acc0 = {0.f, 0.f, 0.f, 0.f};
    f32x4 acc1 = {0.f, 0.f, 0.f, 0.f};

#pragma unroll
    for (int kb = 0; kb < 18; ++kb) {
        const int n  = kb >> 1;
        const int hp = h + n / 3;
        const int wp = w0 + row + (n % 3);
        const int cb = (kb & 1) * 32 + g * 8;
        const bf16x8 a  = *(const bf16x8*)(xtb + ((size_t)hp * WP + wp) * 64 + cb);
        const bf16x8 b0 = *(const bf16x8*)(Bp + (size_t)(kb * 2 + 0) * 512);
        const bf16x8 b1 = *(const bf16x8*)(Bp + (size_t)(kb * 2 + 1) * 512);
        acc0 = __builtin_amdgcn_mfma_f32_16x16x32_bf16(a, b0, acc0, 0, 0, 0);
        acc1 = __builtin_amdgcn_mfma_f32_16x16x32_bf16(a, b1, acc1, 0, 0, 0);
    }

    const int hwb = (p0 + 4 * g) & 16383;
    {
        const int o = row;
        float4 v = make_float4(acc0[0] + b_off[o], acc0[1] + b_off[o],
                               acc0[2] + b_off[o], acc0[3] + b_off[o]);
        *(float4*)&off[((size_t)b * NOFF + o) * HW + hwb] = v;
    }
    if (row < 2) {
        const int o = 16 + row;
        float4 v = make_float4(acc1[0] + b_off[o], acc1[1] + b_off[o],
                               acc1[2] + b_off[o], acc1[3] + b_off[o]);
        *(float4*)&off[((size_t)b * NOFF + o) * HW + hwb] = v;
    }
}

// ---------------------------------------------------------------------------
// k_fuse (r14/r19 proven, 86.2/86.3 us): gather -> global xoff (block's
// slice, L2-hot) -> __syncthreads (drains stores) -> r4-proven GEMM on
// waves 0-1. grid = B*HW/32 = 2048 blocks of 256 (32 px/block).
// ---------------------------------------------------------------------------
__global__ __launch_bounds__(256) void k_fuse(
    const unsigned short* __restrict__ xt, const float* __restrict__ off,
    unsigned short* __restrict__ xoff, const unsigned short* __restrict__ wB,
    const float* __restrict__ b_def, float* __restrict__ out)
{
    const int tid   = threadIdx.x;
    const int lane  = tid & 63;
    const int wv    = tid >> 6;
    const int pxblk = blockIdx.x;
    const int b     = pxblk >> 9;
    const int h     = (pxblk >> 2) & 127;
    const int w0    = (pxblk & 3) * 32;

    __shared__ uint4  geoI[9][32];    // byte offsets into xt[b] (idx*128)
    __shared__ float4 geoG[9][32];

    // ---- phase 1: geometry (lane = pixel), r4-proven formulas ----
    if (lane < 32) {
        const int wpix = w0 + lane;
        const float* offp = off + ((size_t)b * NOFF) * HW + h * W_ + wpix;
        for (int n = wv; n < 9; n += 4) {
            const float ox = offp[(size_t)n * HW];
            const float oy = offp[(size_t)(n + 9) * HW];
            const float px = (float)(h + n / 3) + ox;
            const float py = (float)(wpix + n % 3) + oy;
            const float flx = floorf(px), fly = floorf(py);
            const float qlx = fminf(fmaxf(flx, 0.f), 129.f);
            const float qly = fminf(fmaxf(fly, 0.f), 129.f);
            const float qrx = fminf(fmaxf(flx + 1.f, 0.f), 129.f);
            const float qry = fminf(fmaxf(fly + 1.f, 0.f), 129.f);
            const float pxc = fminf(fmaxf(px, 0.f), 129.f);
            const float pyc = fminf(fmaxf(py, 0.f), 129.f);
            const float gxl = 1.f + (qlx - pxc);
            const float gxr = 1.f - (qrx - pxc);
            const float gyl = 1.f + (qly - pyc);
            const float gyr = 1.f - (qry - pyc);
            const int xl = (int)qlx, yl = (int)qly, xr = (int)qrx, yr = (int)qry;
            geoI[n][lane] = make_uint4((unsigned)((xl * WP + yl) * 128),
                                       (unsigned)((xr * WP + yr) * 128),
                                       (unsigned)((xl * WP + yr) * 128),
                                       (unsigned)((xr * WP + yl) * 128));
            geoG[n][lane] = make_float4(gxl * gyl, gxr * gyr, gxl * gyr, gxr * gyl);
        }
    }
    __syncthreads();

    // ---- phase 2: gather (lane = channel), coalesced bf16 corner loads ----
    const char* xtb2 = (const char*)(xt + (size_t)b * (HP * WP * 64)) + lane * 2;
    unsigned short* xo = xoff + (size_t)(pxblk * 32) * 576;

#pragma unroll 1
    for (int pxi = 0; pxi < 8; ++pxi) {
        const int pxl = wv * 8 + pxi;
#pragma unroll 3
        for (int n = 0; n < 9; ++n) {
            const uint4  gi = geoI[n][pxl];
            const float4 gg = geoG[n][pxl];
            const float vlt = bf2f(*(const unsigned short*)(xtb2 + gi.x));
            const float vrb = bf2f(*(const unsigned short*)(xtb2 + gi.y));
            const float vlb = bf2f(*(const unsigned short*)(xtb2 + gi.z));
            const float vrt = bf2f(*(const unsigned short*)(xtb2 + gi.w));
            const float v = fmaf(gg.x, vlt, fmaf(gg.y, vrb,
                            fmaf(gg.z, vlb, gg.w * vrt)));
            xo[(size_t)pxl * 576 + n * 64 + lane] = f2bf(v);
        }
    }

    // drain stores (compiler emits s_waitcnt vmcnt(0) before s_barrier),
    // then waves 0-1 consume this block's xoff slice from L2.
    __syncthreads();
    if (wv >= 2) return;

    // ---- phase 3: GEMM (r4-proven k_gemm inner loop, verbatim) ----
    const int row = lane & 15;
    const int g   = lane >> 4;

    const unsigned short* Ap = xoff + (size_t)(pxblk * 32 + wv * 16 + row) * 576 + g * 8;
    const unsigned short* Bp = wB + (size_t)lane * 8;

    f32x4 acc0 = {0.f, 0.f, 0.f, 0.f};
    f32x4 acc1 = {0.f, 0.f, 0.f, 0.f};
    f32x4 acc2 = {0.f, 0.f, 0.f, 0.f};
    f32x4 acc3 = {0.f, 0.f, 0.f, 0.f};

#pragma unroll 3
    for (int kb = 0; kb < 18; ++kb) {
        const bf16x8 a  = *(const bf16x8*)(Ap + kb * 32);
        const bf16x8 b0 = *(const bf16x8*)(Bp + (size_t)(kb * 4 + 0) * 512);
        const bf16x8 b1 = *(const bf16x8*)(Bp + (size_t)(kb * 4 + 1) * 512);
        const bf16x8 b2 = *(const bf16x8*)(Bp + (size_t)(kb * 4 + 2) * 512);
        const bf16x8 b3 = *(const bf16x8*)(Bp + (size_t)(kb * 4 + 3) * 512);
        acc0 = __builtin_amdgcn_mfma_f32_16x16x32_bf16(a, b0, acc0, 0, 0, 0);
        acc1 = __builtin_amdgcn_mfma_f32_16x16x32_bf16(a, b1, acc1, 0, 0, 0);
        acc2 = __builtin_amdgcn_mfma_f32_16x16x32_bf16(a, b2, acc2, 0, 0, 0);
        acc3 = __builtin_amdgcn_mfma_f32_16x16x32_bf16(a, b3, acc3, 0, 0, 0);
    }

    const int p_base = pxblk * 32 + wv * 16 + 4 * g;
#pragma unroll
    for (int i = 0; i < 4; ++i) {
        const int o = i * 16 + row;
        const float bias = b_def[o];
        const f32x4 A = (i == 0) ? acc0 : (i == 1) ? acc1 : (i == 2) ? acc2 : acc3;
#pragma unroll
        for (int r = 0; r < 4; ++r) {
            const int p  = p_base + r;
            const int bb = p >> 14;
            const int hw = p & 16383;
            out[((size_t)(bb * COUT + o)) * HW + hw] = A[r] + bias;
        }
    }
}

// ===========================================================================
extern "C" void kernel_launch(void* const* d_in, const int* in_sizes, int n_in,
                              void* d_out, int out_size, void* d_ws, size_t ws_size,
                              hipStream_t stream)
{
    const float* x     = (const float*)d_in[0];
    const float* w_off = (const float*)d_in[1];
    const float* b_off = (const float*)d_in[2];
    const float* w_def = (const float*)d_in[3];
    const float* b_def = (const float*)d_in[4];
    float* out = (float*)d_out;

    char* ws = (char*)d_ws;
    // wB   : bf16 36,864                    73,728 B @ 0
    // wBo  : bf16 18,432                    36,864 B @ 73,728
    // xt   : bf16 [B][130][130][64]      8,652,800 B @ 110,592
    // off  : f32 [B][18][HW]             4,718,592 B @ 8,763,392
    // xoff : bf16 65536 x 576           75,497,472 B @ 13,481,984
    unsigned short* wB   = (unsigned short*)(ws + 0);
    unsigned short* wBo  = (unsigned short*)(ws + 73728);
    unsigned short* xt   = (unsigned short*)(ws + 110592);
    float*          off  = (float*)(ws + 8763392);
    unsigned short* xoff = (unsigned short*)(ws + 13481984);

    k_prep<<<B_ * HP, 256, 0, stream>>>(x, xt, w_def, w_off, wB, wBo);
    k_offconv_mfma<<<B_ * HW / 64, 256, 0, stream>>>(xt, wBo, b_off, off);
    k_fuse<<<B_ * HW / 32, 256, 0, stream>>>(xt, off, xoff, wB, b_def, out);
}